// Round 11
// baseline (363.928 us; speedup 1.0000x reference)
//
#include <hip/hip_runtime.h>

// PatchMatch propagation, B=2, H=W=64, corr (B,H,W,H,W) f32.
// Anti-diagonal wavefront, one wave per batch; lane r owns sweep-row r.
// R11: worker blocks 0,1 byte-identical to R4 (best: 334us) except lane 0
// publishes the current diagonal to d_ws (device-scope store). Blocks
// {8,16,24,32} / {9,17,25,33} are DIAGONAL PREFETCHERS for worker 0 / 1:
// under the empirical blockIdx%8->XCD round-robin they share the worker's
// XCD L2 (not its CU), and stream the ENTIRE 1MB of per-pixel maps of
// diagonal d+2 (positions known a priori -- no speculation) so the sweep's
// data-dependent taps first-touch as L2 hits instead of L3/HBM misses.
// Atomic (device-scope) flag ops + bounded polls -> no cross-XCD hang risk.

struct __attribute__((packed, aligned(4))) f2u { float x, y; };

__device__ __forceinline__ float clamp63(float v) {
    return fminf(fmaxf(v, 0.0f), 63.0f);
}

// Bilinear sample with zero padding, bit-exact vs reference.
__device__ __forceinline__ float bsample(const float* __restrict__ m, float x, float y) {
    float x0f = floorf(x), y0f = floorf(y);
    float wx1 = __fsub_rn(x, x0f);
    float wy1 = __fsub_rn(y, y0f);
    float wx0 = __fsub_rn(1.0f, wx1);
    float wy0 = __fsub_rn(1.0f, wy1);
    int x0 = (int)x0f, y0 = (int)y0f;
    int x1 = x0 + 1, y1 = y0 + 1;
    int y1c = min(y1, 63);
    int bx = min(x0, 62);
    f2u p0 = *(const f2u*)(m + y0 * 64 + bx);
    f2u p1 = *(const f2u*)(m + y1c * 64 + bx);
    bool hi = (x0 > 62);
    float v00 = hi ? p0.y : p0.x;
    float v10 = (x1 <= 63) ? p0.y : 0.0f;
    float v01 = hi ? p1.y : p1.x;
    v01 = (y1 <= 63) ? v01 : 0.0f;
    float v11 = ((x1 <= 63) && (y1 <= 63)) ? p1.y : 0.0f;
    float t0 = __fmul_rn(__fmul_rn(wx0, wy0), v00);
    float t1 = __fmul_rn(__fmul_rn(wx1, wy0), v10);
    float t2 = __fmul_rn(__fmul_rn(wx0, wy1), v01);
    float t3 = __fmul_rn(__fmul_rn(wx1, wy1), v11);
    return __fadd_rn(__fadd_rn(__fadd_rn(t0, t1), t2), t3);
}

__constant__ const int c_dys[4] = {1, -1, -1, 1};
__constant__ const int c_dxs[4] = {1, -1, 1, -1};

__global__ __launch_bounds__(1024, 1) void MatchingPropagator_65180423685702_kernel(
        const float* __restrict__ raw,    // (B,2,64,64)
        const float* __restrict__ corr,   // (B,64,64,64,64)
        const float* __restrict__ noise,  // (3,B,64,64,2)
        float* __restrict__ out,          // (B,2,64,64)
        int* __restrict__ ws) {           // progress flags: ws[0], ws[64]
    const int blk = blockIdx.x;
    const int tid = threadIdx.x;

    if (blk >= 2) {
        // ---------------- prefetcher blocks ----------------
        const int wrk = blk & 7;                  // target worker (XCD guess)
        if (wrk > 1 || blk < 8) return;           // idle filler block
        const int rank = (blk >> 3) - 1;          // 0..3
        int* flag = ws + wrk * 64;
        const float* __restrict__ corrb = corr + (size_t)wrk * 64 * 64 * 4096;
        int last_t = -1000;
        int polls = 0;
        while (polls < 300000) {
            int v = __hip_atomic_load(flag, __ATOMIC_RELAXED, __HIP_MEMORY_SCOPE_AGENT);
            if (v >= 512) break;                               // worker done
            if (v < -2) { ++polls; __builtin_amdgcn_s_sleep(8); continue; }  // poison
            int t = v + 2;                                     // lookahead
            if (t == last_t) { ++polls; __builtin_amdgcn_s_sleep(2); continue; }
            last_t = t;
            int kt = t >> 7;
            if (kt > 3) { ++polls; __builtin_amdgcn_s_sleep(2); continue; }
            int dd = min(t & 127, 126);
            const int dy = c_dys[kt], dx = c_dxs[kt];
            // stream the 64 maps of diagonal dd: 4096 threads, 64 per map
            const int gid = rank * 1024 + tid;
            const int r = gid >> 6, sub = gid & 63;
            const int c = dd - r;
            if (c >= 0 && c < 64) {
                const int i = (dy > 0) ? r : 63 - r;
                const int j = (dx > 0) ? c : 63 - c;
                const float4* mp = (const float4*)(corrb + (size_t)(i * 64 + j) * 4096);
                float acc = 0.0f;
#pragma unroll
                for (int q = 0; q < 16; ++q) {
                    float4 v4 = mp[sub + q * 64];
                    acc += v4.x + v4.y + v4.z + v4.w;
                }
                asm volatile("" :: "v"(acc));   // keep loads live
            }
        }
        return;
    }

    // ---------------- worker block (R4's proven kernel + flag stores) --------
    const int b = blk;
    const float* __restrict__ corrb = corr + (size_t)b * 64 * 64 * 4096;
    int* flag = ws + b * 64;
    if (tid == 0)
        __hip_atomic_store(flag, -2, __ATOMIC_RELAXED, __HIP_MEMORY_SCOPE_AGENT);

    __shared__ float lx[4096];
    __shared__ float ly[4096];
    __shared__ float ls[4096];

    // init: transpose-load coords, compute initial scores (parallel)
    for (int p = tid; p < 4096; p += blockDim.x) {
        float x = raw[(size_t)b * 8192 + p];
        float y = raw[(size_t)b * 8192 + 4096 + p];
        lx[p] = x; ly[p] = y;
        ls[p] = bsample(corrb + (size_t)p * 4096, x, y);
    }
    __syncthreads();

    const int dys[4] = {1, -1, -1, 1};
    const int dxs[4] = {1, -1, 1, -1};

#pragma unroll
    for (int k = 0; k < 4; ++k) {
        const int dy = dys[k], dx = dxs[k];
        const float fdy = (float)dy, fdx = (float)dx;
        if (tid < 64) {
            const int r = tid;
            const int i = (dy > 0) ? r : 63 - r;
            const float* rowbase = corrb + (size_t)i * 64 * 4096;
            float cx = 0.0f, cy = 0.0f;
            for (int d = 0; d < 127; ++d) {
                if (tid == 0)
                    __hip_atomic_store(flag, k * 128 + d, __ATOMIC_RELAXED,
                                       __HIP_MEMORY_SCOPE_AGENT);
                float vnx = __shfl_up(cx, 1);
                float vny = __shfl_up(cy, 1);
                const int c = d - r;
                if (c >= 0 && c < 64) {
                    const int j = (dx > 0) ? c : 63 - c;
                    const int p = i * 64 + j;
                    const float* m = rowbase + (size_t)j * 4096;
                    float px = lx[p], py = ly[p], ps = ls[p];
                    float vcx = clamp63(vnx);
                    float vcy = clamp63(__fadd_rn(vny, fdy));
                    float hcx = clamp63(__fadd_rn(cx, fdx));
                    float hcy = clamp63(cy);
                    float vx0f = floorf(vcx), vy0f = floorf(vcy);
                    float hx0f = floorf(hcx), hy0f = floorf(hcy);
                    int vx0 = (int)vx0f, vy0 = (int)vy0f;
                    int hx0 = (int)hx0f, hy0 = (int)hy0f;
                    int vx1 = vx0 + 1, vy1 = vy0 + 1;
                    int hx1 = hx0 + 1, hy1 = hy0 + 1;
                    int vy1c = min(vy1, 63), hy1c = min(hy1, 63);
                    int vbx = min(vx0, 62), hbx = min(hx0, 62);
                    f2u A0 = *(const f2u*)(m + vy0 * 64 + vbx);
                    f2u A1 = *(const f2u*)(m + vy1c * 64 + vbx);
                    f2u B0 = *(const f2u*)(m + hy0 * 64 + hbx);
                    f2u B1 = *(const f2u*)(m + hy1c * 64 + hbx);
                    float vwx1 = __fsub_rn(vcx, vx0f), vwy1 = __fsub_rn(vcy, vy0f);
                    float vwx0 = __fsub_rn(1.0f, vwx1), vwy0 = __fsub_rn(1.0f, vwy1);
                    float hwx1 = __fsub_rn(hcx, hx0f), hwy1 = __fsub_rn(hcy, hy0f);
                    float hwx0 = __fsub_rn(1.0f, hwx1), hwy0 = __fsub_rn(1.0f, hwy1);
                    float vw00 = __fmul_rn(vwx0, vwy0), vw10 = __fmul_rn(vwx1, vwy0);
                    float vw01 = __fmul_rn(vwx0, vwy1), vw11 = __fmul_rn(vwx1, vwy1);
                    float hw00 = __fmul_rn(hwx0, hwy0), hw10 = __fmul_rn(hwx1, hwy0);
                    float hw01 = __fmul_rn(hwx0, hwy1), hw11 = __fmul_rn(hwx1, hwy1);
                    bool vhi = (vx0 > 62), hhi = (hx0 > 62);
                    float a00 = vhi ? A0.y : A0.x;
                    float a10 = (vx1 <= 63) ? A0.y : 0.0f;
                    float a01 = vhi ? A1.y : A1.x;
                    a01 = (vy1 <= 63) ? a01 : 0.0f;
                    float a11 = ((vx1 <= 63) && (vy1 <= 63)) ? A1.y : 0.0f;
                    float b00 = hhi ? B0.y : B0.x;
                    float b10 = (hx1 <= 63) ? B0.y : 0.0f;
                    float b01 = hhi ? B1.y : B1.x;
                    b01 = (hy1 <= 63) ? b01 : 0.0f;
                    float b11 = ((hx1 <= 63) && (hy1 <= 63)) ? B1.y : 0.0f;
                    float vs = __fadd_rn(__fadd_rn(__fadd_rn(
                                   __fmul_rn(vw00, a00), __fmul_rn(vw10, a10)),
                                   __fmul_rn(vw01, a01)), __fmul_rn(vw11, a11));
                    float hs = __fadd_rn(__fadd_rn(__fadd_rn(
                                   __fmul_rn(hw00, b00), __fmul_rn(hw10, b10)),
                                   __fmul_rn(hw01, b01)), __fmul_rn(hw11, b11));
                    bool uv = (vs > ps) && (r > 0);
                    float ux = uv ? vcx : px;
                    float uy = uv ? vcy : py;
                    float us = uv ? vs : ps;
                    bool uh = (hs > us) && (c > 0);
                    cx = uh ? hcx : ux;
                    cy = uh ? hcy : uy;
                    float fs = uh ? hs : us;
                    lx[p] = cx; ly[p] = cy; ls[p] = fs;
                }
            }
        }
        __syncthreads();

        // random search (elementwise, all 1024 threads)
        if (k < 3) {
            const float* nz = noise + ((size_t)k * 2 + b) * 8192;
            for (int p = tid; p < 4096; p += blockDim.x) {
                float x = lx[p], y = ly[p], s = ls[p];
                float ex = nz[p * 2 + 0], ey = nz[p * 2 + 1];
                float nx = fmaxf(__fadd_rn(x, __fmul_rn(3.0f, ex)), 0.0f);
                float ny = fmaxf(__fadd_rn(y, __fmul_rn(3.0f, ey)), 0.0f);
                // faithful reference oddity: boundary hit overwrites BOTH channels
                if (nx >= 64.0f) { nx = 63.0f; ny = 63.0f; }
                if (ny >= 64.0f) { nx = 63.0f; ny = 63.0f; }
                float ns = bsample(corrb + (size_t)p * 4096, nx, ny);
                if (ns > __fmul_rn(1.05f, s)) {
                    lx[p] = nx; ly[p] = ny; ls[p] = ns;
                }
            }
            __syncthreads();
        }
    }

    if (tid == 0)
        __hip_atomic_store(flag, 1000, __ATOMIC_RELAXED, __HIP_MEMORY_SCOPE_AGENT);

    // output: (B,2,H,W)
    for (int p = tid; p < 4096; p += blockDim.x) {
        out[(size_t)b * 8192 + p] = lx[p];
        out[(size_t)b * 8192 + 4096 + p] = ly[p];
    }
}

extern "C" void kernel_launch(void* const* d_in, const int* in_sizes, int n_in,
                              void* d_out, int out_size, void* d_ws, size_t ws_size,
                              hipStream_t stream) {
    const float* raw   = (const float*)d_in[0];
    const float* corr  = (const float*)d_in[1];
    const float* noise = (const float*)d_in[2];
    float* out = (float*)d_out;
    int* ws = (int*)d_ws;
    (void)in_sizes; (void)n_in; (void)out_size; (void)ws_size;
    // blocks 0,1 = workers; blocks 8,16,24,32 / 9,17,25,33 = prefetchers
    // (same-XCD under blockIdx%8 round-robin); others exit immediately.
    MatchingPropagator_65180423685702_kernel<<<34, 1024, 0, stream>>>(
        raw, corr, noise, out, ws);
}